// Round 2
// baseline (507.525 us; speedup 1.0000x reference)
//
#include <hip/hip_runtime.h>
#include <hip/hip_bf16.h>

#define NB     32
#define TLEN   4096
#define ENCH   512
#define ATTH   256
#define OUTD   80
#define SPKD   64
#define KW     31
#define ATTR   10

// One block per batch element. Everything in one dispatch:
//  0) zero output row
//  1) argmax(prev_attention) -> band [lo,hi]
//  2) prenet chain -> per-batch bias[256] (kept in LDS)
//  3) band logits: 5 groups of 4 positions, thread=(q,c)
//  4) band softmax + scatter
__global__ __launch_bounds__(1024) void fused_kernel(
    const float* __restrict__ input_enc, // [N,T,512]
    const float* __restrict__ input_dec, // [N,80]
    const float* __restrict__ pa,        // [N,T]
    const float* __restrict__ spkr_vec,  // [N,64]
    const int*   __restrict__ lengths,   // [N]
    const float* __restrict__ speed,     // [N]
    const float* __restrict__ W_enc,     // [512,256]
    const float* __restrict__ b_enc,     // [256]
    const float* __restrict__ W_spkr,    // [64,256]
    const float* __restrict__ conv_w,    // [256,31]
    const float* __restrict__ W_dec,     // [512,256]
    const float* __restrict__ W_speed,   // [256]
    const float* __restrict__ Wp1,       // [144,1024]
    const float* __restrict__ bp1,       // [1024]
    const float* __restrict__ Wp2,       // [1024,512]
    const float* __restrict__ bp2,       // [512]
    const float* __restrict__ W_proj,    // [256]
    float* __restrict__ out)             // [N,T]
{
  const int n   = blockIdx.x;
  const int tid = threadIdx.x;

  __shared__ float s_dec[144];
  __shared__ float s_h1[1024];
  __shared__ float s_op[512];
  __shared__ __align__(16) float s_red[8 * 512];
  __shared__ float s_av[1024];
  __shared__ int   s_ai[1024];
  __shared__ float s_bias[256];
  __shared__ float s_enc[4][ENCH];
  __shared__ float s_pa[52];
  __shared__ float s_part[16];
  __shared__ float s_logits[20];
  __shared__ int   s_lo, s_hi;

  // ---- 0) zero the output row (harness poisons d_out with 0xAA every launch)
  ((float4*)(out + (size_t)n * TLEN))[tid] = make_float4(0.f, 0.f, 0.f, 0.f);

  // ---- stage dec_in = concat(input_dec, spkr_vec)
  if (tid < OUTD)      s_dec[tid] = input_dec[n * OUTD + tid];
  else if (tid < 144)  s_dec[tid] = spkr_vec[n * SPKD + (tid - OUTD)];

  // ---- 1) argmax over prev_attention[n,:] (first occurrence on ties)
  {
    const float* p = pa + (size_t)n * TLEN;
    float bv = -1.f; int bi = 0;
    #pragma unroll
    for (int k = 0; k < TLEN / 1024; k++) {
      int t = tid + k * 1024;        // increasing t: strict > keeps first index
      float v = p[t];
      if (v > bv) { bv = v; bi = t; }
    }
    s_av[tid] = bv; s_ai[tid] = bi;
    __syncthreads();                 // also covers s_dec
    for (int s = 512; s > 0; s >>= 1) {
      if (tid < s) {
        float ov = s_av[tid + s]; int oi = s_ai[tid + s];
        float mv = s_av[tid];     int mi = s_ai[tid];
        if (ov > mv || (ov == mv && oi < mi)) { s_av[tid] = ov; s_ai[tid] = oi; }
      }
      __syncthreads();
    }
    if (tid == 0) {
      int mi = s_ai[0];
      s_lo = max(mi - (ATTR - 1), 0);
      s_hi = min(mi + (ATTR - 1), lengths[n] - 1);
    }
  }

  // ---- 2a) h1 = relu(dec_in @ Wp1 + bp1)
  {
    float acc = bp1[tid];
    #pragma unroll 4
    for (int i = 0; i < 144; i++)
      acc = fmaf(s_dec[i], Wp1[i * 1024 + tid], acc);
    s_h1[tid] = fmaxf(acc, 0.f);
  }
  __syncthreads();                   // publishes s_h1, s_lo, s_hi

  // ---- stage pa band for the conv (width 19 + 30 halo, padded to 52)
  if (tid < 52) {
    int idx = s_lo - (KW / 2) + tid;
    s_pa[tid] = (idx >= 0 && idx < TLEN) ? pa[(size_t)n * TLEN + idx] : 0.f;
  }

  // ---- 2b) out_prenet = relu(h1 @ Wp2 + bp2)  (8-way K-split, float4)
  {
    const int g = tid & 127, sl = tid >> 7;
    const int k0 = g * 4;
    float4 acc = make_float4(0.f, 0.f, 0.f, 0.f);
    for (int j = sl; j < 1024; j += 8) {
      float hv = s_h1[j];
      float4 w = *(const float4*)(Wp2 + (size_t)j * 512 + k0);
      acc.x = fmaf(hv, w.x, acc.x);
      acc.y = fmaf(hv, w.y, acc.y);
      acc.z = fmaf(hv, w.z, acc.z);
      acc.w = fmaf(hv, w.w, acc.w);
    }
    *(float4*)(s_red + sl * 512 + k0) = acc;
    __syncthreads();
    if (tid < 512) {
      float v = bp2[tid];
      #pragma unroll
      for (int s2 = 0; s2 < 8; s2++) v += s_red[s2 * 512 + tid];
      s_op[tid] = fmaxf(v, 0.f);
    }
    __syncthreads();
  }

  // ---- 2c) bias = out_prenet @ W_dec + softsign(spkr @ W_spkr) + speed*W_speed
  {
    const int c = tid & 255, sl = tid >> 8;   // 4-way K-split
    float acc = 0.f;
    const int kb = sl * 128;
    #pragma unroll 4
    for (int k = kb; k < kb + 128; k++)
      acc = fmaf(s_op[k], W_dec[k * 256 + c], acc);
    s_red[sl * 256 + c] = acc;
    __syncthreads();
    if (tid < 256) {
      float b = s_red[tid] + s_red[256 + tid] + s_red[512 + tid] + s_red[768 + tid];
      float sp = 0.f;
      #pragma unroll 4
      for (int i = 0; i < 64; i++)
        sp = fmaf(s_dec[OUTD + i], W_spkr[i * 256 + tid], sp);
      sp = sp / (1.f + fabsf(sp));
      s_bias[tid] = b + sp + speed[n] * W_speed[tid];
    }
  }
  __syncthreads();

  // ---- 3) band logits: 5 groups of 4 positions; thread = (q = tid>>8, c = tid&255)
  const int lo = s_lo, hi = s_hi;
  const int q  = tid >> 8;
  const int c  = tid & 255;
  const float be = b_enc[c];
  const float wp = W_proj[c];
  const float bs = s_bias[c];

  for (int g = 0; g < 5; g++) {
    // stage 4 enc rows (2048 floats, 2 per thread)
    {
      int e0 = tid, e1 = tid + 1024;
      int q0 = e0 >> 9, i0 = e0 & 511;
      int q1 = e1 >> 9, i1 = e1 & 511;
      int t0 = lo + g * 4 + q0;
      int t1 = lo + g * 4 + q1;
      s_enc[q0][i0] = (t0 <= hi) ? input_enc[((size_t)n * TLEN + t0) * ENCH + i0] : 0.f;
      s_enc[q1][i1] = (t1 <= hi) ? input_enc[((size_t)n * TLEN + t1) * ENCH + i1] : 0.f;
    }
    __syncthreads();

    float a0 = 0.f, a1 = 0.f;
    #pragma unroll 8
    for (int i = 0; i < ENCH; i += 2) {
      a0 = fmaf(s_enc[q][i],     W_enc[i * 256 + c],       a0);
      a1 = fmaf(s_enc[q][i + 1], W_enc[(i + 1) * 256 + c], a1);
    }
    float a = a0 + a1;

    const int slot = g * 4 + q;
    float cv = 0.f;
    #pragma unroll
    for (int k = 0; k < KW; k++)
      cv = fmaf(s_pa[slot + k], conv_w[c * KW + k], cv);

    float ss = a + be;
    ss = ss / (1.f + fabsf(ss));
    float v = tanhf(ss + bs + cv) * wp;

    #pragma unroll
    for (int off = 32; off > 0; off >>= 1) v += __shfl_down(v, off);
    if ((tid & 63) == 0) s_part[tid >> 6] = v;
    __syncthreads();
    if (tid < 4) {
      float s = s_part[tid * 4] + s_part[tid * 4 + 1]
              + s_part[tid * 4 + 2] + s_part[tid * 4 + 3];
      int t = lo + g * 4 + tid;
      s_logits[g * 4 + tid] = (t <= hi) ? s : -__builtin_inff();
    }
    __syncthreads();   // protect s_enc/s_part reuse next group
  }

  // ---- 4) band softmax + scatter (wave 0 only)
  if (tid < 64) {
    float l = (tid < 20) ? s_logits[tid] : -__builtin_inff();
    float m = l;
    #pragma unroll
    for (int off = 32; off > 0; off >>= 1) m = fmaxf(m, __shfl_down(m, off));
    m = __shfl(m, 0);
    float e = __expf(l - m);           // -inf -> 0
    float s = e;
    #pragma unroll
    for (int off = 32; off > 0; off >>= 1) s += __shfl_down(s, off);
    s = __shfl(s, 0);
    int t = lo + tid;
    if (tid < 20 && t <= hi)
      out[(size_t)n * TLEN + t] = e / s;
  }
}

// ---------------------------------------------------------------------------
extern "C" void kernel_launch(void* const* d_in, const int* in_sizes, int n_in,
                              void* d_out, int out_size, void* d_ws, size_t ws_size,
                              hipStream_t stream) {
  const float* input_enc = (const float*)d_in[0];
  const float* input_dec = (const float*)d_in[1];
  const float* pa        = (const float*)d_in[2];
  const float* spkr_vec  = (const float*)d_in[3];
  const int*   lengths   = (const int*)  d_in[4];
  const float* speed     = (const float*)d_in[5];
  const float* W_enc     = (const float*)d_in[6];
  const float* b_enc     = (const float*)d_in[7];
  const float* W_spkr    = (const float*)d_in[8];
  const float* conv_w    = (const float*)d_in[9];
  const float* W_dec     = (const float*)d_in[10];
  const float* W_speed   = (const float*)d_in[11];
  const float* Wp1       = (const float*)d_in[12];
  const float* bp1       = (const float*)d_in[13];
  const float* Wp2       = (const float*)d_in[14];
  const float* bp2       = (const float*)d_in[15];
  const float* W_proj    = (const float*)d_in[16];
  // d_in[17] = b_proj — cancels in the softmax, unused.

  float* out = (float*)d_out;

  hipLaunchKernelGGL(fused_kernel, dim3(NB), dim3(1024), 0, stream,
                     input_enc, input_dec, pa, spkr_vec, lengths, speed,
                     W_enc, b_enc, W_spkr, conv_w, W_dec, W_speed,
                     Wp1, bp1, Wp2, bp2, W_proj, out);
}

// Round 3
// 441.084 us; speedup vs baseline: 1.1506x; 1.1506x over previous
//
#include <hip/hip_runtime.h>
#include <hip/hip_bf16.h>

#define NB     32
#define TLEN   4096
#define ENCH   512
#define ATTH   256
#define OUTD   80
#define SPKD   64
#define KW     31
#define ATTR   10

// ---------------------------------------------------------------------------
// Kernel A: per-batch block. Zero output row, argmax(prev_attention),
// prenet chain -> per-batch bias[256] = out_prenet@W_dec + softsign(spkr@W_spkr)
//                                      + speed*W_speed
// ---------------------------------------------------------------------------
__global__ __launch_bounds__(1024) void prep_kernel(
    const float* __restrict__ pa,        // [N,T]
    const float* __restrict__ input_dec, // [N,80]
    const float* __restrict__ spkr_vec,  // [N,64]
    const float* __restrict__ speed,     // [N]
    const float* __restrict__ Wp1,       // [144,1024]
    const float* __restrict__ bp1,       // [1024]
    const float* __restrict__ Wp2,       // [1024,512]
    const float* __restrict__ bp2,       // [512]
    const float* __restrict__ W_dec,     // [512,256]
    const float* __restrict__ W_spkr,    // [64,256]
    const float* __restrict__ W_speed,   // [256]
    const int*   __restrict__ lengths,   // [N]
    float* __restrict__ out,             // [N,T]
    int* __restrict__ ws_idx,            // [N,2] -> lo, hi
    float* __restrict__ ws_bias)         // [N,256]
{
  const int n   = blockIdx.x;
  const int tid = threadIdx.x;

  __shared__ float s_dec[144];
  __shared__ float s_h1[1024];
  __shared__ float s_op[512];
  __shared__ __align__(16) float s_red[8 * 512];
  __shared__ float s_av[1024];
  __shared__ int   s_ai[1024];

  // ---- zero the output row (harness poisons d_out with 0xAA every launch)
  ((float4*)(out + (size_t)n * TLEN))[tid] = make_float4(0.f, 0.f, 0.f, 0.f);

  // ---- stage dec_in = concat(input_dec, spkr_vec)
  if (tid < OUTD)      s_dec[tid] = input_dec[n * OUTD + tid];
  else if (tid < 144)  s_dec[tid] = spkr_vec[n * SPKD + (tid - OUTD)];

  // ---- argmax over prev_attention[n,:] (first occurrence on ties)
  {
    const float* p = pa + (size_t)n * TLEN;
    float bv = -1.f; int bi = 0;
    #pragma unroll
    for (int k = 0; k < TLEN / 1024; k++) {
      int t = tid + k * 1024;        // increasing t: strict > keeps first index
      float v = p[t];
      if (v > bv) { bv = v; bi = t; }
    }
    s_av[tid] = bv; s_ai[tid] = bi;
    __syncthreads();                 // also covers s_dec
    for (int s = 512; s > 0; s >>= 1) {
      if (tid < s) {
        float ov = s_av[tid + s]; int oi = s_ai[tid + s];
        float mv = s_av[tid];     int mi = s_ai[tid];
        if (ov > mv || (ov == mv && oi < mi)) { s_av[tid] = ov; s_ai[tid] = oi; }
      }
      __syncthreads();
    }
    if (tid == 0) {
      int mi = s_ai[0];
      ws_idx[n * 2]     = max(mi - (ATTR - 1), 0);
      ws_idx[n * 2 + 1] = min(mi + (ATTR - 1), lengths[n] - 1);
    }
  }

  // ---- h1 = relu(dec_in @ Wp1 + bp1)
  {
    float acc = bp1[tid];
    #pragma unroll 4
    for (int i = 0; i < 144; i++)
      acc = fmaf(s_dec[i], Wp1[i * 1024 + tid], acc);
    s_h1[tid] = fmaxf(acc, 0.f);
  }
  __syncthreads();

  // ---- out_prenet = relu(h1 @ Wp2 + bp2)  (8-way K-split, float4)
  {
    const int g = tid & 127, sl = tid >> 7;
    const int k0 = g * 4;
    float4 acc = make_float4(0.f, 0.f, 0.f, 0.f);
    for (int j = sl; j < 1024; j += 8) {
      float hv = s_h1[j];
      float4 w = *(const float4*)(Wp2 + (size_t)j * 512 + k0);
      acc.x = fmaf(hv, w.x, acc.x);
      acc.y = fmaf(hv, w.y, acc.y);
      acc.z = fmaf(hv, w.z, acc.z);
      acc.w = fmaf(hv, w.w, acc.w);
    }
    *(float4*)(s_red + sl * 512 + k0) = acc;
    __syncthreads();
    if (tid < 512) {
      float v = bp2[tid];
      #pragma unroll
      for (int s2 = 0; s2 < 8; s2++) v += s_red[s2 * 512 + tid];
      s_op[tid] = fmaxf(v, 0.f);
    }
    __syncthreads();
  }

  // ---- bias = out_prenet @ W_dec + softsign(spkr @ W_spkr) + speed*W_speed
  {
    const int c = tid & 255, sl = tid >> 8;   // 4-way K-split
    float acc = 0.f;
    const int kb = sl * 128;
    #pragma unroll 4
    for (int k = kb; k < kb + 128; k++)
      acc = fmaf(s_op[k], W_dec[k * 256 + c], acc);
    s_red[sl * 256 + c] = acc;
    __syncthreads();
    if (tid < 256) {
      float b = s_red[tid] + s_red[256 + tid] + s_red[512 + tid] + s_red[768 + tid];
      float sp = 0.f;
      #pragma unroll 4
      for (int i = 0; i < 64; i++)
        sp = fmaf(s_dec[OUTD + i], W_spkr[i * 256 + tid], sp);
      sp = sp / (1.f + fabsf(sp));
      ws_bias[n * 256 + tid] = b + sp + speed[n] * W_speed[tid];
    }
  }
}

// ---------------------------------------------------------------------------
// Kernel B: one block per (batch, band position). 256 threads.
// 4-way K-split GEMV with float4 W_enc loads, conv_w staged in LDS.
// logit[t] = sum_c tanh( softsign(enc@W_enc + b_enc)[c] + bias[c] + conv[t,c] ) * W_proj[c]
// ---------------------------------------------------------------------------
__global__ __launch_bounds__(256) void band_kernel(
    const float* __restrict__ input_enc, // [N,T,512]
    const float* __restrict__ pa,        // [N,T]
    const float* __restrict__ W_enc,     // [512,256]
    const float* __restrict__ b_enc,     // [256]
    const float* __restrict__ conv_w,    // [256,31]
    const float* __restrict__ W_proj,    // [256]
    const int*   __restrict__ ws_idx,    // [N,2]
    const float* __restrict__ ws_bias,   // [N,256]
    float* __restrict__ ws_logits)       // [N,20]
{
  const int n   = blockIdx.x;
  const int j   = blockIdx.y;            // band offset 0..19
  const int tid = threadIdx.x;

  const int lo = ws_idx[n * 2];
  const int hi = ws_idx[n * 2 + 1];
  const int t  = lo + j;

  if (t > hi) {
    if (tid == 0) ws_logits[n * 20 + j] = -__builtin_inff();
    return;
  }

  __shared__ __align__(16) float s_enc[ENCH];
  __shared__ float s_pa[KW];
  __shared__ __align__(16) float s_red[4 * 256];
  __shared__ float s_cw[ATTH * KW];     // 31 KB
  __shared__ float s_part[4];

  // stage conv_w (coalesced, all threads)
  for (int k2 = tid; k2 < ATTH * KW; k2 += 256) s_cw[k2] = conv_w[k2];
  // stage enc row (float4) and pa halo
  if (tid < 128)
    ((float4*)s_enc)[tid] = ((const float4*)(input_enc + ((size_t)n * TLEN + t) * ENCH))[tid];
  else if (tid < 128 + KW) {
    int idx = t - (KW / 2) + (tid - 128);
    s_pa[tid - 128] = (idx >= 0 && idx < TLEN) ? pa[(size_t)n * TLEN + idx] : 0.f;
  }
  __syncthreads();

  // ---- K-split GEMV: wave sl covers i in [sl*128, sl*128+128), lane handles 4 channels
  {
    const int sl = tid >> 6;
    const int l4 = tid & 63;             // channel group: c = l4*4 .. +3
    const float4* W4 = (const float4*)W_enc;
    float4 acc = make_float4(0.f, 0.f, 0.f, 0.f);
    const int i0 = sl * 128;
    #pragma unroll 8
    for (int i = i0; i < i0 + 128; i++) {
      float e  = s_enc[i];               // wave-uniform -> LDS broadcast
      float4 w = W4[i * 64 + l4];        // 1 KiB contiguous per wave per i
      acc.x = fmaf(e, w.x, acc.x);
      acc.y = fmaf(e, w.y, acc.y);
      acc.z = fmaf(e, w.z, acc.z);
      acc.w = fmaf(e, w.w, acc.w);
    }
    *(float4*)(s_red + sl * 256 + l4 * 4) = acc;
  }
  __syncthreads();

  // ---- per-channel pointwise: thread = channel c
  {
    const int c = tid;
    float y = s_red[c] + s_red[256 + c] + s_red[512 + c] + s_red[768 + c];
    float cv = 0.f;
    #pragma unroll
    for (int k = 0; k < KW; k++)
      cv = fmaf(s_pa[k], s_cw[c * KW + k], cv);
    float ss = y + b_enc[c];
    ss = ss / (1.f + fabsf(ss));
    float v = tanhf(ss + ws_bias[n * 256 + c] + cv) * W_proj[c];

    #pragma unroll
    for (int off = 32; off > 0; off >>= 1) v += __shfl_down(v, off);
    if ((tid & 63) == 0) s_part[tid >> 6] = v;
  }
  __syncthreads();
  if (tid == 0)
    ws_logits[n * 20 + j] = s_part[0] + s_part[1] + s_part[2] + s_part[3];
}

// ---------------------------------------------------------------------------
// Kernel C: band softmax + scatter (global max shift cancels; band max used)
// ---------------------------------------------------------------------------
__global__ __launch_bounds__(64) void softmax_kernel(
    const float* __restrict__ ws_logits, // [N,20]
    const int*   __restrict__ ws_idx,    // [N,2]
    float* __restrict__ out)             // [N,T]
{
  const int n   = blockIdx.x;
  const int tid = threadIdx.x;
  const int lo  = ws_idx[n * 2];
  const int hi  = ws_idx[n * 2 + 1];

  float l = (tid < 20) ? ws_logits[n * 20 + tid] : -__builtin_inff();
  float m = l;
  #pragma unroll
  for (int off = 32; off > 0; off >>= 1) m = fmaxf(m, __shfl_down(m, off));
  m = __shfl(m, 0);
  float e = __expf(l - m);           // -inf -> 0
  float s = e;
  #pragma unroll
  for (int off = 32; off > 0; off >>= 1) s += __shfl_down(s, off);
  s = __shfl(s, 0);

  int t = lo + tid;
  if (tid < 20 && t <= hi)
    out[(size_t)n * TLEN + t] = e / s;
}

// ---------------------------------------------------------------------------
extern "C" void kernel_launch(void* const* d_in, const int* in_sizes, int n_in,
                              void* d_out, int out_size, void* d_ws, size_t ws_size,
                              hipStream_t stream) {
  const float* input_enc = (const float*)d_in[0];
  const float* input_dec = (const float*)d_in[1];
  const float* pa        = (const float*)d_in[2];
  const float* spkr_vec  = (const float*)d_in[3];
  const int*   lengths   = (const int*)  d_in[4];
  const float* speed     = (const float*)d_in[5];
  const float* W_enc     = (const float*)d_in[6];
  const float* b_enc     = (const float*)d_in[7];
  const float* W_spkr    = (const float*)d_in[8];
  const float* conv_w    = (const float*)d_in[9];
  const float* W_dec     = (const float*)d_in[10];
  const float* W_speed   = (const float*)d_in[11];
  const float* Wp1       = (const float*)d_in[12];
  const float* bp1       = (const float*)d_in[13];
  const float* Wp2       = (const float*)d_in[14];
  const float* bp2       = (const float*)d_in[15];
  const float* W_proj    = (const float*)d_in[16];
  // d_in[17] = b_proj — cancels in the softmax, unused.

  float* out = (float*)d_out;

  int*   ws_idx    = (int*)d_ws;                                    // [N,2]
  float* ws_bias   = (float*)((char*)d_ws + 256);                   // [N,256]
  float* ws_logits = (float*)((char*)d_ws + 256 + NB * 256 * 4);    // [N,20]

  hipLaunchKernelGGL(prep_kernel, dim3(NB), dim3(1024), 0, stream,
                     pa, input_dec, spkr_vec, speed, Wp1, bp1, Wp2, bp2,
                     W_dec, W_spkr, W_speed, lengths, out, ws_idx, ws_bias);

  hipLaunchKernelGGL(band_kernel, dim3(NB, 20), dim3(256), 0, stream,
                     input_enc, pa, W_enc, b_enc, conv_w, W_proj,
                     ws_idx, ws_bias, ws_logits);

  hipLaunchKernelGGL(softmax_kernel, dim3(NB), dim3(64), 0, stream,
                     ws_logits, ws_idx, out);
}